// Round 11
// baseline (4940.289 us; speedup 1.0000x reference)
//
#include <hip/hip_runtime.h>

#define NT 512
#define B_ 32768
#define D_ 256
#define L_ 4
#define K_ 2048
#define BM 64
#define NBLK (B_/BM)      // 512
#define BETA_ 0.25f

#define OUT_LOSS   8388608
#define OUT_UNUSED 8388609
#define OUT_INDS   8388610

// ws layout: counts int[L*K] @0 ; cnorm float[L*K] @32768 ; lpart float[NBLK] @65536

__global__ __launch_bounds__(256) void rq_prep(const float* __restrict__ cb,
                                               int* __restrict__ counts,
                                               float* __restrict__ cnorm) {
  int cw = blockIdx.x * 256 + threadIdx.x;
  if (cw >= L_ * K_) return;
  counts[cw] = 0;
  const float4* cb4 = (const float4*)cb;
  float s = 0.f;
  for (int d4 = 0; d4 < 64; ++d4) {
    float4 v = cb4[(size_t)cw * 64 + d4];
    s = __fadd_rn(s, __fmul_rn(v.x, v.x));
    s = __fadd_rn(s, __fmul_rn(v.y, v.y));
    s = __fadd_rn(s, __fmul_rn(v.z, v.z));
    s = __fadd_rn(s, __fmul_rn(v.w, v.w));
  }
  cnorm[cw] = s;
}

// SCALAR-PIPE KERNEL. R4-R10 plateau analysis: the per-CU LDS instruction pipe
// (~12 cyc per ds_*_b128, shared by all 8 waves) was the wall — every variant
// issued ~136 LDS ops/chunk/wave (x reads + code reads + code staging).
// Fix: lane = row. The code operand of each FMA is then WAVE-UNIFORM, so the
// codebook streams through the SCALAR pipe (s_load via readfirstlane-uniform
// pointers) into SGPRs, never touching LDS or VGPR-vector loads.
//   - LDS ops/chunk/wave: 136 -> 64 (xv only), all lane-linear (0 conflicts)
//   - dot is lane-complete -> no DPP reduce at all
//   - hot VGPRs ~15 -> compiler freely pipelines s_load/ds_read
__global__ __attribute__((amdgpu_flat_work_group_size(NT, NT)))
void rq_main(
    const float* __restrict__ x, const float* __restrict__ cb,
    float* __restrict__ out, int* __restrict__ counts,
    const float* __restrict__ cnorm, float* __restrict__ lpart) {
  __shared__ float4 xst[64][65];      // [d4][row] residual tile (transposed), pad col
  __shared__ float  red_v[8][64];
  __shared__ int    red_i[8][64];
  __shared__ float  xxs[64];
  __shared__ int    ind_s[64];
  __shared__ float  lred[NT];

  const int tid  = threadIdx.x;
  const int lane = tid & 63;          // = row within the block's 64-row tile
  const int wave = tid >> 6;
  const int wu   = __builtin_amdgcn_readfirstlane(wave);   // uniform wave id
  const int row0 = blockIdx.x * BM;
  const float4* x4  = (const float4*)x;
  const float4* cb4 = (const float4*)cb;

  // ---- stage x tile (level-0 residual): global read coalesced (lane = d4),
  // write transposed xst[d4][row]; 8 lanes/bank-quad balanced, once per kernel ----
  {
    float4 v[8];
    #pragma unroll
    for (int it = 0; it < 8; ++it)
      v[it] = x4[(size_t)(row0 + wave + (it << 3)) * 64 + lane];
    #pragma unroll
    for (int it = 0; it < 8; ++it)
      xst[lane][wave + (it << 3)] = v[it];
  }

  float lsum = 0.f;
  float4* out4 = (float4*)out;

  for (int l = 0; l < L_; ++l) {
    __syncthreads();   // xst (stage/update) visible to all waves

    // per-row |x|^2 in ref (d4-ascending, xyzw) order — REQUIRED for argmin
    // fidelity (snaps distances onto the reference rounding grid).
    if (tid < 64) {
      float s = 0.f;
      for (int d4 = 0; d4 < 64; ++d4) {
        float4 v = xst[d4][tid];
        s = __fadd_rn(s, __fmul_rn(v.x, v.x));
        s = __fadd_rn(s, __fmul_rn(v.y, v.y));
        s = __fadd_rn(s, __fmul_rn(v.z, v.z));
        s = __fadd_rn(s, __fmul_rn(v.w, v.w));
      }
      xxs[tid] = s;
    }
    __syncthreads();   // xxs visible

    const float xx = xxs[lane];       // this lane's row norm
    float bv = 3.4e38f; int bi = 0;
    const float* cnl = cnorm + l * K_;
    // uniform base of this wave's 8 codes at level l (advances 64 codes/chunk)
    const float* cwl = cb + ((size_t)l * K_ + (size_t)wu * 8) * 256;

    for (int ch = 0; ch < 32; ++ch) {
      const float* cwp = cwl + (size_t)ch * (64 * 256);

      float acc[8];
      #pragma unroll
      for (int jj = 0; jj < 8; ++jj) acc[jj] = 0.f;

      // dot(row=lane, code=ch*64 + wu*8 + jj) over d ascending. xv is one
      // lane-linear ds_read_b128 per d4; code values are s_load_dwordx4
      // (uniform) -> scalar pipe, zero LDS/VALU load cost.
      #pragma unroll 8
      for (int t = 0; t < 64; ++t) {
        const float4 xv = xst[t][lane];
        #pragma unroll
        for (int jj = 0; jj < 8; ++jj) {
          const float4 c = *(const float4*)(cwp + jj * 256 + t * 4);
          acc[jj] = fmaf(xv.x, c.x, acc[jj]);
          acc[jj] = fmaf(xv.y, c.y, acc[jj]);
          acc[jj] = fmaf(xv.z, c.z, acc[jj]);
          acc[jj] = fmaf(xv.w, c.w, acc[jj]);
        }
      }

      // reference distance form: (|x|^2 - 2*dot) + |c|^2 ; jj ascending keeps
      // first-occurrence tie semantics within the wave's code set
      const int kb0 = (ch << 6) + (wu << 3);
      #pragma unroll
      for (int jj = 0; jj < 8; ++jj) {
        const float cn = cnl[kb0 + jj];   // uniform -> scalar load
        float s = __fadd_rn(__fsub_rn(xx, __fmul_rn(2.0f, acc[jj])), cn);
        if (s < bv) { bv = s; bi = kb0 + jj; }
      }
    }

    // ---- cross-wave argmin per row (explicit index tie-break handles the
    // interleaved code ownership across waves) ----
    red_v[wave][lane] = bv;
    red_i[wave][lane] = bi;
    __syncthreads();
    if (tid < 64) {
      float bv_ = red_v[0][tid]; int bi_ = red_i[0][tid];
      #pragma unroll
      for (int w = 1; w < 8; ++w) {
        float v = red_v[w][tid]; int ii = red_i[w][tid];
        if (v < bv_ || (v == bv_ && ii < bi_)) { bv_ = v; bi_ = ii; }
      }
      ind_s[tid] = bi_;
      out[(size_t)OUT_INDS + (size_t)(row0 + tid) * L_ + l] = (float)bi_;
      atomicAdd(&counts[l * K_ + bi_], 1);
    }
    __syncthreads();

    // ---- residual update + loss + quantized accumulated directly in out
    // (l==0 stores, l>=1 RMW by the same thread: bit-identical to a fadd
    //  chain from 0). Thread cell: (row r = wave+8it, d4 = lane). ----
    #pragma unroll
    for (int it = 0; it < 8; ++it) {
      const int r = wave + (it << 3);
      const size_t oidx = (size_t)(row0 + r) * 64 + lane;
      float4 xv = xst[lane][r];
      float4 cv = cb4[(size_t)(l * K_ + ind_s[r]) * 64 + lane];
      float tx = __fsub_rn(cv.x, xv.x); float qx = __fadd_rn(xv.x, tx); float nx = __fsub_rn(xv.x, qx);
      float ty = __fsub_rn(cv.y, xv.y); float qy = __fadd_rn(xv.y, ty); float ny = __fsub_rn(xv.y, qy);
      float tz = __fsub_rn(cv.z, xv.z); float qz = __fadd_rn(xv.z, tz); float nz = __fsub_rn(xv.z, qz);
      float tw = __fsub_rn(cv.w, xv.w); float qw = __fadd_rn(xv.w, tw); float nw = __fsub_rn(xv.w, qw);
      float4 prev = (l == 0) ? make_float4(0.f, 0.f, 0.f, 0.f) : out4[oidx];
      out4[oidx] = make_float4(__fadd_rn(prev.x, qx), __fadd_rn(prev.y, qy),
                               __fadd_rn(prev.z, qz), __fadd_rn(prev.w, qw));
      float ex = __fsub_rn(xv.x, cv.x);
      float ey = __fsub_rn(xv.y, cv.y);
      float ez = __fsub_rn(xv.z, cv.z);
      float ew = __fsub_rn(xv.w, cv.w);
      lsum = __fadd_rn(lsum, __fmul_rn(ex, ex));
      lsum = __fadd_rn(lsum, __fmul_rn(ey, ey));
      lsum = __fadd_rn(lsum, __fmul_rn(ez, ez));
      lsum = __fadd_rn(lsum, __fmul_rn(ew, ew));
      xst[lane][r] = make_float4(nx, ny, nz, nw);
    }
  }

  // ---- deterministic per-block loss partial ----
  lred[tid] = lsum;
  __syncthreads();
  for (int s = NT / 2; s > 0; s >>= 1) {
    if (tid < s) lred[tid] += lred[tid + s];
    __syncthreads();
  }
  if (tid == 0) lpart[blockIdx.x] = lred[0];
}

__global__ __launch_bounds__(256) void rq_final(const int* __restrict__ counts,
                                                const float* __restrict__ lpart,
                                                float* __restrict__ out) {
  __shared__ double fs[256];
  __shared__ int    is_[256];
  int tid = threadIdx.x;
  double ls = 0.0;
  for (int i = tid; i < NBLK; i += 256) ls += (double)lpart[i];
  int uz = 0;
  for (int i = tid; i < L_ * K_; i += 256) uz += (counts[i] == 0) ? 1 : 0;
  fs[tid] = ls; is_[tid] = uz;
  __syncthreads();
  for (int s = 128; s > 0; s >>= 1) {
    if (tid < s) { fs[tid] += fs[tid + s]; is_[tid] += is_[tid + s]; }
    __syncthreads();
  }
  if (tid == 0) {
    out[OUT_LOSS]   = (float)(fs[0] * (double)BETA_ / ((double)B_ * (double)D_ * (double)L_));
    out[OUT_UNUSED] = (float)is_[0];
  }
}

extern "C" void kernel_launch(void* const* d_in, const int* in_sizes, int n_in,
                              void* d_out, int out_size, void* d_ws, size_t ws_size,
                              hipStream_t stream) {
  const float* x  = (const float*)d_in[0];
  const float* cb = (const float*)d_in[1];
  float* out = (float*)d_out;
  int*   counts = (int*)d_ws;
  float* cnorm  = (float*)((char*)d_ws + 32768);
  float* lpart  = (float*)((char*)d_ws + 65536);

  rq_prep<<<(L_ * K_ + 255) / 256, 256, 0, stream>>>(cb, counts, cnorm);
  rq_main<<<NBLK, NT, 0, stream>>>(x, cb, out, counts, cnorm, lpart);
  rq_final<<<1, 256, 0, stream>>>(counts, lpart, out);
}

// Round 12
// 1892.025 us; speedup vs baseline: 2.6111x; 2.6111x over previous
//
#include <hip/hip_runtime.h>

#define NT 512
#define B_ 32768
#define D_ 256
#define L_ 4
#define K_ 2048
#define BM 64
#define NBLK (B_/BM)      // 512
#define BETA_ 0.25f

#define OUT_LOSS   8388608
#define OUT_UNUSED 8388609
#define OUT_INDS   8388610

// ws layout: counts int[L*K] @0 ; cnorm float[L*K] @32768 ; lpart float[NBLK] @65536

__global__ __launch_bounds__(256) void rq_prep(const float* __restrict__ cb,
                                               int* __restrict__ counts,
                                               float* __restrict__ cnorm) {
  int cw = blockIdx.x * 256 + threadIdx.x;
  if (cw >= L_ * K_) return;
  counts[cw] = 0;
  const float4* cb4 = (const float4*)cb;
  float s = 0.f;
  for (int d4 = 0; d4 < 64; ++d4) {
    float4 v = cb4[(size_t)cw * 64 + d4];
    s = __fadd_rn(s, __fmul_rn(v.x, v.x));
    s = __fadd_rn(s, __fmul_rn(v.y, v.y));
    s = __fadd_rn(s, __fmul_rn(v.z, v.z));
    s = __fadd_rn(s, __fmul_rn(v.w, v.w));
  }
  cnorm[cw] = s;
}

template<int CTRL>
__device__ __forceinline__ float dpp_f(float v) {
  return __int_as_float(__builtin_amdgcn_update_dpp(0, __float_as_int(v), CTRL, 0xF, 0xF, true));
}
template<int CTRL>
__device__ __forceinline__ int dpp_i(int v) {
  return __builtin_amdgcn_update_dpp(0, v, CTRL, 0xF, 0xF, true);
}
#define XOR1 0xB1   // quad_perm [1,0,3,2]  == lane^1 (dg bit 0)
#define XOR2 0x4E   // quad_perm [2,3,0,1]  == lane^2 (dg bit 1)

__device__ __forceinline__ void fma_blk(float (&acc)[4][8], const float4 (&xv)[4],
                                        const float4 (&cv)[8]) {
  #pragma unroll
  for (int i = 0; i < 4; ++i)
    #pragma unroll
    for (int j = 0; j < 8; ++j) {
      float a = acc[i][j];
      a = fmaf(xv[i].x, cv[j].x, a);
      a = fmaf(xv[i].y, cv[j].y, a);
      a = fmaf(xv[i].z, cv[j].z, a);
      a = fmaf(xv[i].w, cv[j].w, a);
      acc[i][j] = a;
    }
}
__device__ __forceinline__ void fma_ini(float (&acc)[4][8], const float4 (&xv)[4],
                                        const float4 (&cv)[8]) {
  // fma(a,b,0) == mul(a,b) bit-exactly
  #pragma unroll
  for (int i = 0; i < 4; ++i)
    #pragma unroll
    for (int j = 0; j < 8; ++j) {
      float a = __fmul_rn(xv[i].x, cv[j].x);
      a = fmaf(xv[i].y, cv[j].y, a);
      a = fmaf(xv[i].z, cv[j].z, a);
      a = fmaf(xv[i].w, cv[j].w, a);
      acc[i][j] = a;
    }
}

// PIPELINED R7: the R4-R9 plateau is a lockstep convoy — all waves burst
// ds_reads (VALU idle) then burst FMAs (LDS idle); the pipes ADD. R9's fix
// failed because acc[8][8] left no registers to hold a prefetched bank.
// R7's acc[4][8] geometry (passed, 0 conflicts) fits a double-banked xv in
// the 128-reg cap: per t-iter, source order = load cv(t) -> load xv(t+1,
// other bank) -> FMA(t). In-order lgkm returns make the FMA wait
// lgkmcnt(4): cv ready, xv(t+1) stays in flight under 128 FMAs of cover.
__global__ __attribute__((amdgpu_flat_work_group_size(NT, NT), amdgpu_waves_per_eu(1)))
void rq_main(
    const float* __restrict__ x, const float* __restrict__ cb,
    float* __restrict__ out, int* __restrict__ counts,
    const float* __restrict__ cnorm, float* __restrict__ lpart) {
  __shared__ float4 xs[64][65];       // 65KB residual tile, LINEAR, pad col 64
  __shared__ float4 cs[64][64];       // 64KB codebook chunk, LINEAR; WAVE-PRIVATE rows w*8..w*8+7
  __shared__ float  red_v[8][64];
  __shared__ int    red_i[8][64];
  __shared__ float  xxs[64];
  __shared__ int    ind_s[64];
  __shared__ float  lred[NT];

  const int tid  = threadIdx.x;
  const int lane = tid & 63;
  const int wave = tid >> 6;
  const int dg   = lane & 3;          // D-group: d4 === dg (mod 4)
  const int p    = lane >> 2;         // row-group: rows p*4..p*4+3
  const int row0 = blockIdx.x * BM;
  const float4* x4  = (const float4*)x;
  const float4* cb4 = (const float4*)cb;

  // ---- stage x tile (level-0 residual), fully linear ----
  {
    float4 v[8];
    #pragma unroll
    for (int it = 0; it < 8; ++it)
      v[it] = x4[(size_t)(row0 + wave + (it << 3)) * 64 + lane];
    #pragma unroll
    for (int it = 0; it < 8; ++it)
      xs[wave + (it << 3)][lane] = v[it];
  }

  // ---- pre-stage cs chunk 0 (wave-private rows), linear ----
  float4 st[8];
  #pragma unroll
  for (int it = 0; it < 8; ++it)
    st[it] = cb4[(size_t)(wave * 8 + it) * 64 + lane];
  #pragma unroll
  for (int it = 0; it < 8; ++it)
    cs[wave * 8 + it][lane] = st[it];

  // bases (all loop offsets are compile-time immediates)
  const float4* xb = &xs[p * 4][dg];
  const float4* cvp[4];
  #pragma unroll
  for (int jj = 0; jj < 4; ++jj) cvp[jj] = &cs[wave * 8 + (jj ^ dg)][dg];

  float lsum = 0.f;
  const int kb = (wave << 3) | dg;    // lane's first candidate code within a chunk
  float4* out4 = (float4*)out;

  for (int l = 0; l < L_; ++l) {
    __syncthreads();   // xs (stage/update) visible to all waves

    // per-row |x|^2 in ref (d4-ascending, xyzw) order — REQUIRED for argmin
    // fidelity (snaps distances onto the reference rounding grid).
    if (tid < 64) {
      float s = 0.f;
      for (int d4 = 0; d4 < 64; ++d4) {
        float4 v = xs[tid][d4];
        s = __fadd_rn(s, __fmul_rn(v.x, v.x));
        s = __fadd_rn(s, __fmul_rn(v.y, v.y));
        s = __fadd_rn(s, __fmul_rn(v.z, v.z));
        s = __fadd_rn(s, __fmul_rn(v.w, v.w));
      }
      xxs[tid] = s;
    }
    __syncthreads();   // xxs visible

    float xxr[4];
    #pragma unroll
    for (int i = 0; i < 4; ++i) xxr[i] = xxs[p * 4 + i];

    float bv[4]; int bi[4];
    #pragma unroll
    for (int i = 0; i < 4; ++i) { bv[i] = 3.4e38f; bi[i] = 0; }
    const float* cnl = cnorm + l * K_;

    // NOTE: no __syncthreads inside this loop. cs rows are wave-private, xs is
    // read-only here; all cs WAR/RAW hazards are within-wave (in-order LDS pipe).
    for (int ch = 0; ch < 32; ++ch) {
      // issue global loads for next chunk (hidden under the t-loop)
      {
        int tn = l * 32 + ch + 1; if (tn > 127) tn = 127;
        const float4* src = cb4 + (size_t)tn * 4096;
        #pragma unroll
        for (int it = 0; it < 8; ++it)
          st[it] = src[(size_t)(wave * 8 + it) * 64 + lane];
      }
      const float cn0 = cnl[(ch << 5) + ((ch << 5)) ? 0 : 0];   // (placeholder removed below)
      const float cnA = cnl[(ch << 6) + kb];
      const float cnB = cnl[(ch << 6) + kb + 4];
      (void)cn0;

      float acc[4][8];
      float4 xva[4], xvb[4], cv[8];

      // banked t-loop: t even -> xva, t odd -> xvb; at iter t we load cv(t)
      // FIRST, then xv(t+1) into the other bank, then 128 FMAs on bank(t).
      #define LXA(T) { xva[0]=xb[(T)*4]; xva[1]=xb[65+(T)*4]; xva[2]=xb[130+(T)*4]; xva[3]=xb[195+(T)*4]; }
      #define LXB(T) { xvb[0]=xb[(T)*4]; xvb[1]=xb[65+(T)*4]; xvb[2]=xb[130+(T)*4]; xvb[3]=xb[195+(T)*4]; }
      #define LC(T)  { cv[0]=cvp[0][(T)*4]; cv[1]=cvp[1][(T)*4]; cv[2]=cvp[2][(T)*4]; cv[3]=cvp[3][(T)*4]; \
                       cv[4]=cvp[0][(T)*4+256]; cv[5]=cvp[1][(T)*4+256]; cv[6]=cvp[2][(T)*4+256]; cv[7]=cvp[3][(T)*4+256]; }
      LXA(0);
      LC(0);  LXB(1);  fma_ini(acc, xva, cv);
      LC(1);  LXA(2);  fma_blk(acc, xvb, cv);
      LC(2);  LXB(3);  fma_blk(acc, xva, cv);
      LC(3);  LXA(4);  fma_blk(acc, xvb, cv);
      LC(4);  LXB(5);  fma_blk(acc, xva, cv);
      LC(5);  LXA(6);  fma_blk(acc, xvb, cv);
      LC(6);  LXB(7);  fma_blk(acc, xva, cv);
      LC(7);  LXA(8);  fma_blk(acc, xvb, cv);
      LC(8);  LXB(9);  fma_blk(acc, xva, cv);
      LC(9);  LXA(10); fma_blk(acc, xvb, cv);
      LC(10); LXB(11); fma_blk(acc, xva, cv);
      LC(11); LXA(12); fma_blk(acc, xvb, cv);
      LC(12); LXB(13); fma_blk(acc, xva, cv);
      LC(13); LXA(14); fma_blk(acc, xvb, cv);
      LC(14); LXB(15); fma_blk(acc, xva, cv);
      LC(15);          fma_blk(acc, xvb, cv);
      #undef LXA
      #undef LXB
      #undef LC

      // write staged next chunk into this wave's cs rows (all reads of the
      // current chunk retired; in-order DS pipe orders writes after them)
      #pragma unroll
      for (int it = 0; it < 8; ++it)
        cs[wave * 8 + it][lane] = st[it];

      // DPP reduce across the 4 dg-lanes (quad): register pairing j^bit keeps
      // the code consistent. acc[i][0] -> code w*8+dg; acc[i][4] -> w*8+4+dg.
      #pragma unroll
      for (int i = 0; i < 4; ++i) {
        acc[i][0] += dpp_f<XOR1>(acc[i][1]);
        acc[i][2] += dpp_f<XOR1>(acc[i][3]);
        acc[i][0] += dpp_f<XOR2>(acc[i][2]);
        acc[i][4] += dpp_f<XOR1>(acc[i][5]);
        acc[i][6] += dpp_f<XOR1>(acc[i][7]);
        acc[i][4] += dpp_f<XOR2>(acc[i][6]);
      }

      // reference distance form: (|x|^2 - 2*dot) + |c|^2; smaller index first
      const int kidx = (ch << 6) + kb;
      #pragma unroll
      for (int i = 0; i < 4; ++i) {
        float s0 = __fadd_rn(__fsub_rn(xxr[i], __fmul_rn(2.0f, acc[i][0])), cnA);
        if (s0 < bv[i]) { bv[i] = s0; bi[i] = kidx; }
        float s4 = __fadd_rn(__fsub_rn(xxr[i], __fmul_rn(2.0f, acc[i][4])), cnB);
        if (s4 < bv[i]) { bv[i] = s4; bi[i] = kidx + 4; }
      }
    }

    // ---- in-quad argmin reduce across the 4 dg lanes (ties -> smaller index) ----
    #pragma unroll
    for (int i = 0; i < 4; ++i) {
      { float pv = dpp_f<XOR1>(bv[i]); int pi = dpp_i<XOR1>(bi[i]);
        if (pv < bv[i] || (pv == bv[i] && pi < bi[i])) { bv[i] = pv; bi[i] = pi; } }
      { float pv = dpp_f<XOR2>(bv[i]); int pi = dpp_i<XOR2>(bi[i]);
        if (pv < bv[i] || (pv == bv[i] && pi < bi[i])) { bv[i] = pv; bi[i] = pi; } }
    }
    if (dg == 0) {
      #pragma unroll
      for (int i = 0; i < 4; ++i) {
        red_v[wave][p * 4 + i] = bv[i];
        red_i[wave][p * 4 + i] = bi[i];
      }
    }
    __syncthreads();
    if (tid < 64) {
      float bv_ = red_v[0][tid]; int bi_ = red_i[0][tid];
      #pragma unroll
      for (int w = 1; w < 8; ++w) {
        float v = red_v[w][tid]; int ii = red_i[w][tid];
        if (v < bv_ || (v == bv_ && ii < bi_)) { bv_ = v; bi_ = ii; }
      }
      ind_s[tid] = bi_;
      out[(size_t)OUT_INDS + (size_t)(row0 + tid) * L_ + l] = (float)bi_;
      atomicAdd(&counts[l * K_ + bi_], 1);
    }
    __syncthreads();

    // ---- residual update + loss + quantized accumulated directly in out
    // (l==0 stores, l>=1 RMW by the same thread: bit-identical to a fadd
    //  chain from 0; no dependence on pre-zeroed out). All linear. ----
    #pragma unroll
    for (int it = 0; it < 8; ++it) {
      const int r = wave + (it << 3);
      const size_t oidx = (size_t)(row0 + r) * 64 + lane;
      float4 xv = xs[r][lane];
      float4 cv = cb4[(size_t)(l * K_ + ind_s[r]) * 64 + lane];
      float tx = __fsub_rn(cv.x, xv.x); float qx = __fadd_rn(xv.x, tx); float nx = __fsub_rn(xv.x, qx);
      float ty = __fsub_rn(cv.y, xv.y); float qy = __fadd_rn(xv.y, ty); float ny = __fsub_rn(xv.y, qy);
      float tz = __fsub_rn(cv.z, xv.z); float qz = __fadd_rn(xv.z, tz); float nz = __fsub_rn(xv.z, qz);
      float tw = __fsub_rn(cv.w, xv.w); float qw = __fadd_rn(xv.w, tw); float nw = __fsub_rn(xv.w, qw);
      float4 prev = (l == 0) ? make_float4(0.f, 0.f, 0.f, 0.f) : out4[oidx];
      out4[oidx] = make_float4(__fadd_rn(prev.x, qx), __fadd_rn(prev.y, qy),
                               __fadd_rn(prev.z, qz), __fadd_rn(prev.w, qw));
      float ex = __fsub_rn(xv.x, cv.x);
      float ey = __fsub_rn(xv.y, cv.y);
      float ez = __fsub_rn(xv.z, cv.z);
      float ew = __fsub_rn(xv.w, cv.w);
      lsum = __fadd_rn(lsum, __fmul_rn(ex, ex));
      lsum = __fadd_rn(lsum, __fmul_rn(ey, ey));
      lsum = __fadd_rn(lsum, __fmul_rn(ez, ez));
      lsum = __fadd_rn(lsum, __fmul_rn(ew, ew));
      xs[r][lane] = make_float4(nx, ny, nz, nw);
    }
  }

  // ---- deterministic per-block loss partial ----
  lred[tid] = lsum;
  __syncthreads();
  for (int s = NT / 2; s > 0; s >>= 1) {
    if (tid < s) lred[tid] += lred[tid + s];
    __syncthreads();
  }
  if (tid == 0) lpart[blockIdx.x] = lred[0];
}

__global__ __launch_bounds__(256) void rq_final(const int* __restrict__ counts,
                                                const float* __restrict__ lpart,
                                                float* __restrict__ out) {
  __shared__ double fs[256];
  __shared__ int    is_[256];
  int tid = threadIdx.x;
  double ls = 0.0;
  for (int i = tid; i < NBLK; i += 256) ls += (double)lpart[i];
  int uz = 0;
  for (int i = tid; i < L_ * K_; i += 256) uz += (counts[i] == 0) ? 1 : 0;
  fs[tid] = ls; is_[tid] = uz;
  __syncthreads();
  for (int s = 128; s > 0; s >>= 1) {
    if (tid < s) { fs[tid] += fs[tid + s]; is_[tid] += is_[tid + s]; }
    __syncthreads();
  }
  if (tid == 0) {
    out[OUT_LOSS]   = (float)(fs[0] * (double)BETA_ / ((double)B_ * (double)D_ * (double)L_));
    out[OUT_UNUSED] = (float)is_[0];
  }
}

extern "C" void kernel_launch(void* const* d_in, const int* in_sizes, int n_in,
                              void* d_out, int out_size, void* d_ws, size_t ws_size,
                              hipStream_t stream) {
  const float* x  = (const float*)d_in[0];
  const float* cb = (const float*)d_in[1];
  float* out = (float*)d_out;
  int*   counts = (int*)d_ws;
  float* cnorm  = (float*)((char*)d_ws + 32768);
  float* lpart  = (float*)((char*)d_ws + 65536);

  rq_prep<<<(L_ * K_ + 255) / 256, 256, 0, stream>>>(cb, counts, cnorm);
  rq_main<<<NBLK, NT, 0, stream>>>(x, cb, out, counts, cnorm, lpart);
  rq_final<<<1, 256, 0, stream>>>(counts, lpart, out);
}